// Round 1
// baseline (554.679 us; speedup 1.0000x reference)
//
#include <hip/hip_runtime.h>

// DiffeomorphicLearnerTorch: 8-step Euler flow of a Gaussian-RKHS deformation.
// Per step: sq=rowsq(Z); K=exp((2*Z@Z^T - sq_i - sq_j)/512); Z += DT*(Z@Aaff^T + b + K@A_t)
// Strategy: bf16 MFMA (32x32x16) flash-style fused kernel, fp32 state Z.
//   - k_transpose: A [8][4096][256] f32 -> ATb [8][256][4096] bf16 (B-operand layout)
//   - k_init:      Zb=bf16(X), sq=rowsq(X)
//   - per step: k_flash (256 blocks = 32 i-tiles x 8 j-chunks, 512 thr) -> Opart bf16 [8][N][D]
//               k_update (sum partials + baff, advance fp32 Z, emit Zb/sq)

#define N_PTS 4096
#define DIM   256
#define DT_C  0.125f
#define C1    (1.0f/512.0f)   // 1/(2*rho^2), rho=16

typedef __bf16 bf16x8 __attribute__((ext_vector_type(8)));
typedef float  f32x16 __attribute__((ext_vector_type(16)));
typedef float  f32x4v __attribute__((ext_vector_type(4)));
typedef unsigned int   u32x4 __attribute__((ext_vector_type(4)));
typedef unsigned short u16x4 __attribute__((ext_vector_type(4)));
typedef unsigned short u16x8 __attribute__((ext_vector_type(8)));

__device__ __forceinline__ unsigned short f2bf(float f) {
  unsigned int u = __builtin_bit_cast(unsigned int, f);
  u += 0x7fffu + ((u >> 16) & 1u);          // RNE
  return (unsigned short)(u >> 16);
}
__device__ __forceinline__ float bf2f(unsigned short s) {
  unsigned int u = ((unsigned int)s) << 16;
  return __builtin_bit_cast(float, u);
}

// ---------------- transpose+convert A ----------------
__global__ __launch_bounds__(256) void k_transpose(const float* __restrict__ A,
                                                   unsigned short* __restrict__ ATb) {
  __shared__ float sT[64][65];
  const int j0 = blockIdx.x * 64;
  const int d0 = blockIdx.y * 64;
  const int t  = blockIdx.z;
  const int tid = threadIdx.x;
  const float* Ab = A + (size_t)t * N_PTS * DIM;
  unsigned short* Ob = ATb + (size_t)t * DIM * N_PTS;
#pragma unroll
  for (int i = 0; i < 16; ++i) {
    int e = i * 256 + tid;
    int r = e >> 6, c = e & 63;
    sT[r][c] = Ab[(size_t)(j0 + r) * DIM + d0 + c];
  }
  __syncthreads();
#pragma unroll
  for (int i = 0; i < 16; ++i) {
    int e = i * 256 + tid;
    int r = e >> 6, c = e & 63;          // r: local d, c: local j
    Ob[(size_t)(d0 + r) * N_PTS + j0 + c] = f2bf(sT[c][r]);
  }
}

// ---------------- init: Zb, sq from X ----------------
__global__ __launch_bounds__(256) void k_init(const float* __restrict__ X,
                                              unsigned short* __restrict__ Zb,
                                              float* __restrict__ sq) {
  const int b = blockIdx.x, tid = threadIdx.x;
  const int w = tid >> 6, lane = tid & 63;
#pragma unroll
  for (int rr = 0; rr < 4; ++rr) {
    int row = b * 16 + w * 4 + rr;
    size_t base = (size_t)row * DIM + lane * 4;
    f32x4v z = *(const f32x4v*)(X + base);
    u16x4 zb; float s = 0.f;
#pragma unroll
    for (int i = 0; i < 4; ++i) { zb[i] = f2bf(z[i]); s += z[i] * z[i]; }
    *(u16x4*)(Zb + base) = zb;
#pragma unroll
    for (int off = 32; off > 0; off >>= 1) s += __shfl_down(s, off);
    if (lane == 0) sq[row] = s;
  }
}

// ---------------- fused flash kernel ----------------
// grid: x = chunk (0..7, 512 j's each), y = i-tile (0..31, 128 rows)
// block: 512 threads = 8 waves.
// GEMM1 (S = Zi @ Zj^T): wave (wr1=wid>>1, wc1=wid&1) owns S[wr1*32..+32][wc1*32..+32]
//   A-frags resident in regs (full K=256), B from swizzled sZj.
// GEMM2 (O += P @ Aj): wave (wr2=wid>>2, wc2=wid&3) owns O[wr2*64..+64][wc2*64..+64] (2x2 tiles)
__global__ __launch_bounds__(512, 2) void k_flash(
    const unsigned short* __restrict__ Zb, const float* __restrict__ sqg,
    const unsigned short* __restrict__ ATt,   // [256][4096] bf16 for this step
    const float* __restrict__ Aaff_t,         // [256][256] f32 for this step
    unsigned short* __restrict__ Opart) {
  __shared__ unsigned short sZj[64 * 256];    // 32 KiB, swizzled rows of 512B
  __shared__ unsigned short sAj[256 * 64];    // 32 KiB, swizzled rows of 128B
  __shared__ unsigned short sP [128 * 64];    // 16 KiB, swizzled rows of 128B

  const int tid = threadIdx.x;
  const int lane = tid & 63;
  const int wid = tid >> 6;
  const int chunk = blockIdx.x;
  const int i0 = blockIdx.y * 128;
  const int jbase = chunk * 512;

  const int l31 = lane & 31;
  const int lhi = lane >> 5;      // 0/1
  const int koff = lhi * 8;

  const int wr1 = wid >> 1, wc1 = wid & 1;
  const int wr2 = wid >> 2, wc2 = wid & 3;

  // resident A-fragments for GEMM1: rows i0 + wr1*32 + l31, all K=256
  bf16x8 afrag[16];
  {
    const unsigned short* zr = Zb + (size_t)(i0 + wr1 * 32 + l31) * DIM;
#pragma unroll
    for (int ks = 0; ks < 16; ++ks)
      afrag[ks] = __builtin_bit_cast(bf16x8, *(const u32x4*)(zr + ks * 16 + koff));
  }
  // ei = C1*sq for the 16 C-layout rows of this wave's S tile
  float ei[16];
  {
    const int rbase = i0 + wr1 * 32 + 4 * lhi;
#pragma unroll
    for (int c = 0; c < 16; ++c) ei[c] = C1 * sqg[rbase + (c & 3) + 8 * (c >> 2)];
  }

  f32x16 O[2][2];
#pragma unroll
  for (int rt = 0; rt < 2; ++rt)
#pragma unroll
    for (int ct = 0; ct < 2; ++ct)
#pragma unroll
      for (int i = 0; i < 16; ++i) O[rt][ct][i] = 0.f;

  // affine part folded into chunk 0: O += Zi @ Aaff_t^T  (frags direct from global)
  if (chunk == 0) {
#pragma unroll 1
    for (int ks = 0; ks < 16; ++ks) {
      bf16x8 av[2], bv[2];
#pragma unroll
      for (int rt = 0; rt < 2; ++rt) {
        int row = i0 + wr2 * 64 + rt * 32 + l31;
        av[rt] = __builtin_bit_cast(bf16x8, *(const u32x4*)(Zb + (size_t)row * DIM + ks * 16 + koff));
      }
#pragma unroll
      for (int ct = 0; ct < 2; ++ct) {
        int d = wc2 * 64 + ct * 32 + l31;
        const float* ap = Aaff_t + (size_t)d * DIM + ks * 16 + koff;
        f32x4v f0 = *(const f32x4v*)(ap);
        f32x4v f1 = *(const f32x4v*)(ap + 4);
        u16x8 tmp;
#pragma unroll
        for (int i = 0; i < 4; ++i) { tmp[i] = f2bf(f0[i]); tmp[4 + i] = f2bf(f1[i]); }
        bv[ct] = __builtin_bit_cast(bf16x8, tmp);
      }
#pragma unroll
      for (int rt = 0; rt < 2; ++rt)
#pragma unroll
        for (int ct = 0; ct < 2; ++ct)
          O[rt][ct] = __builtin_amdgcn_mfma_f32_32x32x16_bf16(av[rt], bv[ct], O[rt][ct], 0, 0, 0);
    }
  }

  // ---- j-loop: 8 tiles of 64 ----
  for (int jt = 0; jt < 8; ++jt) {
    const int j0 = jbase + jt * 64;
    __syncthreads();   // previous readers of sZj/sAj/sP done
    // stage sZj [64][256] from Zb (swizzled)
#pragma unroll
    for (int it = 0; it < 4; ++it) {
      int row = it * 16 + (tid >> 5);
      int k8 = (tid & 31) * 8;
      u32x4 v = *(const u32x4*)(Zb + (size_t)(j0 + row) * DIM + k8);
      int blk = tid & 31;
      int b2 = (blk & 24) | ((blk ^ row) & 7);
      *(u32x4*)((char*)sZj + row * 512 + (b2 << 4)) = v;
    }
    // stage sAj [256][64] from ATt (swizzled)
#pragma unroll
    for (int it = 0; it < 4; ++it) {
      int n = it * 64 + (tid >> 3);
      int k8 = (tid & 7) * 8;
      u32x4 v = *(const u32x4*)(ATt + (size_t)n * N_PTS + j0 + k8);
      int b2 = (tid & 7) ^ (n & 7);
      *(u32x4*)((char*)sAj + n * 128 + (b2 << 4)) = v;
    }
    __syncthreads();

    // GEMM1
    f32x16 S;
#pragma unroll
    for (int i = 0; i < 16; ++i) S[i] = 0.f;
    {
      const int brow = wc1 * 32 + l31;
#pragma unroll
      for (int ks = 0; ks < 16; ++ks) {
        int blk = ks * 2 + lhi;
        int b2 = (blk & 24) | ((blk ^ brow) & 7);
        bf16x8 bfr = *(const bf16x8*)((const char*)sZj + brow * 512 + (b2 << 4));
        S = __builtin_amdgcn_mfma_f32_32x32x16_bf16(afrag[ks], bfr, S, 0, 0, 0);
      }
    }
    // P = exp((2S - sqi - sqj)/512) -> sP (bf16, swizzled)
    {
      const int pcol = wc1 * 32 + l31;
      const float ej = C1 * sqg[j0 + pcol];
      const int prbase = wr1 * 32 + 4 * lhi;
      const int off = pcol * 2;
      const int blk = off >> 4;
#pragma unroll
      for (int c = 0; c < 16; ++c) {
        int prow = prbase + (c & 3) + 8 * (c >> 2);
        float arg = 2.f * C1 * S[c] - ei[c] - ej;
        unsigned short pv = f2bf(__expf(arg));
        int b2 = blk ^ (prow & 7);
        *((unsigned short*)((char*)sP + prow * 128 + (b2 << 4) + (off & 15))) = pv;
      }
    }
    __syncthreads();
    // GEMM2: O += P @ Aj
#pragma unroll
    for (int ks = 0; ks < 4; ++ks) {
      const int blkb = ks * 2 + lhi;
      bf16x8 av[2], bv[2];
#pragma unroll
      for (int rt = 0; rt < 2; ++rt) {
        int m = wr2 * 64 + rt * 32 + l31;
        int b2 = blkb ^ (m & 7);
        av[rt] = *(const bf16x8*)((const char*)sP + m * 128 + (b2 << 4));
      }
#pragma unroll
      for (int ct = 0; ct < 2; ++ct) {
        int n = wc2 * 64 + ct * 32 + l31;
        int b2 = blkb ^ (n & 7);
        bv[ct] = *(const bf16x8*)((const char*)sAj + n * 128 + (b2 << 4));
      }
#pragma unroll
      for (int rt = 0; rt < 2; ++rt)
#pragma unroll
        for (int ct = 0; ct < 2; ++ct)
          O[rt][ct] = __builtin_amdgcn_mfma_f32_32x32x16_bf16(av[rt], bv[ct], O[rt][ct], 0, 0, 0);
    }
  }

  // epilogue: O -> Opart[chunk] as bf16
  {
    unsigned short* ob = Opart + (size_t)chunk * N_PTS * DIM;
#pragma unroll
    for (int rt = 0; rt < 2; ++rt)
#pragma unroll
      for (int ct = 0; ct < 2; ++ct) {
        int colb = wc2 * 64 + ct * 32 + l31;
        int rbase = wr2 * 64 + rt * 32 + 4 * lhi;
#pragma unroll
        for (int c = 0; c < 16; ++c) {
          int row = i0 + rbase + (c & 3) + 8 * (c >> 2);
          ob[(size_t)row * DIM + colb] = f2bf(O[rt][ct][c]);
        }
      }
  }
}

// ---------------- update: Z += DT*(sum partials + baff); emit Zb, sq ----------------
__global__ __launch_bounds__(256) void k_update(const float* __restrict__ Zin,
                                                const unsigned short* __restrict__ Opart,
                                                const float* __restrict__ baff_t,
                                                float* __restrict__ Zout,
                                                unsigned short* __restrict__ Zb,
                                                float* __restrict__ sq) {
  const int b = blockIdx.x, tid = threadIdx.x;
  const int w = tid >> 6, lane = tid & 63;
  f32x4v bv = *(const f32x4v*)(baff_t + lane * 4);
#pragma unroll
  for (int rr = 0; rr < 4; ++rr) {
    int row = b * 16 + w * 4 + rr;
    size_t base = (size_t)row * DIM + lane * 4;
    f32x4v z = *(const f32x4v*)(Zin + base);
    f32x4v s = bv;
#pragma unroll
    for (int c = 0; c < 8; ++c) {
      u16x4 p = *(const u16x4*)(Opart + (size_t)c * N_PTS * DIM + base);
#pragma unroll
      for (int i = 0; i < 4; ++i) s[i] += bf2f(p[i]);
    }
    u16x4 zb; float sv = 0.f;
#pragma unroll
    for (int i = 0; i < 4; ++i) {
      z[i] += DT_C * s[i];
      zb[i] = f2bf(z[i]);
      sv += z[i] * z[i];
    }
    *(f32x4v*)(Zout + base) = z;
    *(u16x4*)(Zb + base) = zb;
#pragma unroll
    for (int off = 32; off > 0; off >>= 1) sv += __shfl_down(sv, off);
    if (lane == 0) sq[row] = sv;
  }
}

extern "C" void kernel_launch(void* const* d_in, const int* in_sizes, int n_in,
                              void* d_out, int out_size, void* d_ws, size_t ws_size,
                              hipStream_t stream) {
  const float* X    = (const float*)d_in[0];
  const float* A    = (const float*)d_in[1];
  const float* Aaff = (const float*)d_in[2];
  const float* baff = (const float*)d_in[3];
  float* out = (float*)d_out;

  char* w = (char*)d_ws;
  size_t off = 0;
  unsigned short* ATb = (unsigned short*)(w + off); off += (size_t)8 * DIM * N_PTS * 2;  // 16 MiB
  unsigned short* Zb  = (unsigned short*)(w + off); off += (size_t)N_PTS * DIM * 2;      // 2 MiB
  float* sq  = (float*)(w + off); off += (size_t)N_PTS * 4;
  float* Zf0 = (float*)(w + off); off += (size_t)N_PTS * DIM * 4;
  float* Zf1 = (float*)(w + off); off += (size_t)N_PTS * DIM * 4;
  unsigned short* Opart = (unsigned short*)(w + off); off += (size_t)8 * N_PTS * DIM * 2;
  (void)ws_size; (void)in_sizes; (void)n_in; (void)out_size;

  k_transpose<<<dim3(64, 4, 8), 256, 0, stream>>>(A, ATb);
  k_init<<<256, 256, 0, stream>>>(X, Zb, sq);

  const float* zin = X;
  for (int t = 0; t < 8; ++t) {
    float* zout = (t == 7) ? out : ((t & 1) ? Zf1 : Zf0);
    k_flash<<<dim3(8, 32), 512, 0, stream>>>(
        Zb, sq, ATb + (size_t)t * DIM * N_PTS, Aaff + (size_t)t * DIM * DIM, Opart);
    k_update<<<256, 256, 0, stream>>>(zin, Opart, baff + (size_t)t * DIM, zout, Zb, sq);
    zin = zout;
  }
}